// Round 1
// baseline (173.628 us; speedup 1.0000x reference)
//
#include <hip/hip_runtime.h>
#include <hip/hip_bf16.h>

// Head: out[b,t,h] = softmax_causal( (x@Wq)(x@Wk)^T * 6^-0.5 ) @ (x@Wv)
// B=512 T=128 C=384 H=64. Fully fused: one block per b, bf16 MFMA 16x16x32.

#define B_ 512
#define T_ 128
#define C_ 384
#define H_ 64

typedef __bf16 bf16;
typedef __attribute__((ext_vector_type(8))) __bf16 bf16x8;
typedef __attribute__((ext_vector_type(4))) __bf16 bf16x4;
typedef __attribute__((ext_vector_type(4))) float f32x4;

// LDS element offsets (bf16):
//  Ws  [0,7680)      : 192 rows x 40 (W^T chunk, k-contig, pad 8)
//  Qs  [7680,15872)  : 128 x 64, XOR-swizzled units of 8
//  Ks  [15872,24064) : 128 x 64, swizzled
//  Vts [24064,32256) : 64 x 128 (V^T), swizzled
//  Ps  aliases [7680,24064) : 128 x 128, swizzled  (after barrier)
// total 64512 bytes -> 2 blocks/CU

__launch_bounds__(256, 2)
__global__ void head_fused(const float* __restrict__ x,
                           const float* __restrict__ Wq,
                           const float* __restrict__ Wk,
                           const float* __restrict__ Wv,
                           float* __restrict__ out)
{
    __shared__ bf16 lds[32256];
    bf16* Ws  = lds;
    bf16* Qs  = lds + 7680;
    bf16* Ks  = lds + 15872;
    bf16* Vts = lds + 24064;
    bf16* Ps  = lds + 7680;

    const int tid  = threadIdx.x;
    const int w    = tid >> 6;     // wave 0..3
    const int lane = tid & 63;
    const int lm   = lane & 15;    // fragment row/col index
    const int quad = lane >> 4;    // fragment k-group / row-group
    const int b    = blockIdx.x;

    const float* xb = x + (size_t)b * (T_ * C_);

    // ================= Phase 1: QKV = x[b] @ [Wq|Wk|Wv] =================
    // wave w owns m rows [32w, 32w+32), all 192 n columns
    f32x4 acc[2][12];
#pragma unroll
    for (int i = 0; i < 2; ++i)
#pragma unroll
        for (int t = 0; t < 12; ++t) acc[i][t] = (f32x4){0.f, 0.f, 0.f, 0.f};

    for (int kc = 0; kc < 12; ++kc) {
        // stage W^T chunk: Ws[n][k] = Wcat[kc*32+k][n], n=j*64+h
#pragma unroll
        for (int it = 0; it < 6; ++it) {
            int u   = tid + it * 256;   // [0,1536)
            int h   = u & 63;
            int rem = u >> 6;           // [0,24)
            int j   = rem >> 3;         // 0..2 (wave-uniform)
            int k4  = rem & 7;
            const float* Wp = (j == 0) ? Wq : (j == 1) ? Wk : Wv;
            const float* g  = Wp + (kc * 32 + k4 * 4) * H_ + h;
            float f0 = g[0], f1 = g[64], f2 = g[128], f3 = g[192];
            bf16x4 v4 = {(bf16)f0, (bf16)f1, (bf16)f2, (bf16)f3};
            *(bf16x4*)&Ws[(j * 64 + h) * 40 + k4 * 4] = v4;
        }
        __syncthreads();

        // A fragments straight from global (32B/lane contiguous, coalesced)
        bf16x8 afr[2];
#pragma unroll
        for (int i = 0; i < 2; ++i) {
            const float4* xp =
                (const float4*)(xb + (32 * w + 16 * i + lm) * C_ + kc * 32 + quad * 8);
            float4 p0 = xp[0], p1 = xp[1];
            afr[i] = (bf16x8){(bf16)p0.x, (bf16)p0.y, (bf16)p0.z, (bf16)p0.w,
                              (bf16)p1.x, (bf16)p1.y, (bf16)p1.z, (bf16)p1.w};
        }
#pragma unroll
        for (int tn = 0; tn < 12; ++tn) {
            bf16x8 bfr = *(const bf16x8*)&Ws[(16 * tn + lm) * 40 + quad * 8];
            acc[0][tn] = __builtin_amdgcn_mfma_f32_16x16x32_bf16(afr[0], bfr, acc[0][tn], 0, 0, 0);
            acc[1][tn] = __builtin_amdgcn_mfma_f32_16x16x32_bf16(afr[1], bfr, acc[1][tn], 0, 0, 0);
        }
        __syncthreads();
    }

    // epilogue: Q,K row-major [t][h]; V transposed [h][t]; all swizzled bf16
#pragma unroll
    for (int i = 0; i < 2; ++i) {
#pragma unroll
        for (int tn = 0; tn < 12; ++tn) {
            int gn = 16 * tn + lm;
            int j = gn >> 6, h = gn & 63;
            int m0 = 32 * w + 16 * i + quad * 4;
            if (j == 2) {
                bf16x4 v4 = {(bf16)acc[i][tn][0], (bf16)acc[i][tn][1],
                             (bf16)acc[i][tn][2], (bf16)acc[i][tn][3]};
                int pc = (m0 & 7) | ((((m0 >> 3) ^ (h & 15)) & 15) << 3);
                *(bf16x4*)&Vts[h * 128 + pc] = v4;
            } else {
                bf16* dst = (j == 0) ? Qs : Ks;
#pragma unroll
                for (int r = 0; r < 4; ++r) {
                    int m = m0 + r;
                    int pc = (h & 7) | ((((h >> 3) ^ (m & 7)) & 7) << 3);
                    dst[m * 64 + pc] = (bf16)acc[i][tn][r];
                }
            }
        }
    }
    __syncthreads();

    // ================= Phase 2: attention =================
    const float SCALE = 0.40824829046386307f;  // 6^-0.5
    const int tmg0 = w, tmg1 = 7 - w;          // balanced: (w+1)+(8-w)=9 tiles/wave

    f32x4 sacc[2][8];
#pragma unroll
    for (int i = 0; i < 2; ++i)
#pragma unroll
        for (int t = 0; t < 8; ++t) sacc[i][t] = (f32x4){0.f, 0.f, 0.f, 0.f};

    // S = Q K^T  (skip fully-masked tiles)
#pragma unroll
    for (int i = 0; i < 2; ++i) {
        const int tm = i ? tmg1 : tmg0;
        const int mrow = 16 * tm + lm;
        bf16x8 qa[2];
#pragma unroll
        for (int ks = 0; ks < 2; ++ks) {
            int phys = ((ks * 4 + quad) ^ (mrow & 7)) & 7;
            qa[ks] = *(const bf16x8*)&Qs[mrow * 64 + phys * 8];
        }
#pragma unroll
        for (int tn = 0; tn < 8; ++tn) {
            if (tn <= tm) {
                int nrow = 16 * tn + lm;
#pragma unroll
                for (int ks = 0; ks < 2; ++ks) {
                    int phys = ((ks * 4 + quad) ^ (nrow & 7)) & 7;
                    bf16x8 kb = *(const bf16x8*)&Ks[nrow * 64 + phys * 8];
                    sacc[i][tn] =
                        __builtin_amdgcn_mfma_f32_16x16x32_bf16(qa[ks], kb, sacc[i][tn], 0, 0, 0);
                }
            }
        }
    }

    // softmax, fully in registers; rows live in contiguous 16-lane groups
#pragma unroll
    for (int i = 0; i < 2; ++i) {
        const int tm = i ? tmg1 : tmg0;
#pragma unroll
        for (int r = 0; r < 4; ++r) {
            int m = 16 * tm + quad * 4 + r;
            float mx = -1e30f;
#pragma unroll
            for (int tn = 0; tn < 8; ++tn) {
                if (tn <= tm) {
                    int n = 16 * tn + lm;
                    float v = (n <= m) ? sacc[i][tn][r] * SCALE : -1e30f;
                    sacc[i][tn][r] = v;
                    mx = fmaxf(mx, v);
                }
            }
#pragma unroll
            for (int off = 1; off < 16; off <<= 1) mx = fmaxf(mx, __shfl_xor(mx, off, 16));
            float sum = 0.f;
#pragma unroll
            for (int tn = 0; tn < 8; ++tn) {
                if (tn <= tm) {
                    float e = __expf(sacc[i][tn][r] - mx);
                    sacc[i][tn][r] = e;
                    sum += e;
                }
            }
#pragma unroll
            for (int off = 1; off < 16; off <<= 1) sum += __shfl_xor(sum, off, 16);
            float inv = 1.f / sum;
#pragma unroll
            for (int tn = 0; tn < 8; ++tn) {
                if (tn <= tm) sacc[i][tn][r] *= inv;
            }
        }
    }

    __syncthreads();  // everyone done reading Qs/Ks; Ps aliases them

    // write P (bf16, swizzled). Each wave writes only its own rows.
#pragma unroll
    for (int i = 0; i < 2; ++i) {
        const int tm = i ? tmg1 : tmg0;
#pragma unroll
        for (int tn = 0; tn < 8; ++tn) {
            if (tn <= tm) {
                int n = 16 * tn + lm;
#pragma unroll
                for (int r = 0; r < 4; ++r) {
                    int m = 16 * tm + quad * 4 + r;
                    int pc = (n & 7) | ((((n >> 3) ^ (m & 15)) & 15) << 3);
                    Ps[m * 128 + pc] = (bf16)sacc[i][tn][r];
                }
            }
        }
        if ((tm & 1) == 0) {  // zero the half-covered k-tile (tm even)
            int m = 16 * tm + lm;
            int c0 = 16 * (tm + 1) + quad * 4;
            int pc = (c0 & 7) | ((((c0 >> 3) ^ (m & 15)) & 15) << 3);
            *(bf16x4*)&Ps[m * 128 + pc] =
                (bf16x4){(bf16)0.f, (bf16)0.f, (bf16)0.f, (bf16)0.f};
        }
    }

    // O = P @ V  (k-tiles limited by causal extent; reads only own P rows)
    f32x4 oacc[2][4];
#pragma unroll
    for (int i = 0; i < 2; ++i)
#pragma unroll
        for (int t = 0; t < 4; ++t) oacc[i][t] = (f32x4){0.f, 0.f, 0.f, 0.f};

#pragma unroll
    for (int i = 0; i < 2; ++i) {
        const int tm = i ? tmg1 : tmg0;
        const int mrow = 16 * tm + lm;
        const int nks = (tm + 2) >> 1;
        for (int ks = 0; ks < nks; ++ks) {  // wave-uniform bound
            int unit = ks * 4 + quad;
            int phys = (unit ^ (mrow & 15)) & 15;
            bf16x8 pa = *(const bf16x8*)&Ps[mrow * 128 + phys * 8];
#pragma unroll
            for (int th = 0; th < 4; ++th) {
                int hrow = 16 * th + lm;
                int ph2 = (unit ^ (hrow & 15)) & 15;
                bf16x8 vb = *(const bf16x8*)&Vts[hrow * 128 + ph2 * 8];
                oacc[i][th] =
                    __builtin_amdgcn_mfma_f32_16x16x32_bf16(pa, vb, oacc[i][th], 0, 0, 0);
            }
        }
    }

    // store O fp32 [b][t][h]
    float* ob = out + (size_t)b * (T_ * H_);
#pragma unroll
    for (int i = 0; i < 2; ++i) {
        const int tm = i ? tmg1 : tmg0;
#pragma unroll
        for (int th = 0; th < 4; ++th) {
            int h = 16 * th + lm;
#pragma unroll
            for (int r = 0; r < 4; ++r) {
                int m = 16 * tm + quad * 4 + r;
                ob[m * 64 + h] = oacc[i][th][r];
            }
        }
    }
}

extern "C" void kernel_launch(void* const* d_in, const int* in_sizes, int n_in,
                              void* d_out, int out_size, void* d_ws, size_t ws_size,
                              hipStream_t stream) {
    const float* x  = (const float*)d_in[0];
    const float* Wq = (const float*)d_in[1];
    const float* Wk = (const float*)d_in[2];
    const float* Wv = (const float*)d_in[3];
    float* o = (float*)d_out;
    head_fused<<<dim3(B_), dim3(256), 0, stream>>>(x, Wq, Wk, Wv, o);
}